// Round 3
// baseline (332.740 us; speedup 1.0000x reference)
//
#include <hip/hip_runtime.h>
#include <hip/hip_bf16.h>

// Problem: B=32, L=1024, F=1024, H=1024, D=1024 — inputs fp32, OUTPUT fp32.
//   h1 = feat@W1 + b1; h2 = hidden@W2 + b2; att = tanh(h1 + h2[:,None,:])
//   score = att@Wp; w = softmax_L(score); out[b][f] = sum_l w[b][l]*feat[b][l][f]
//
// R11: R9/R10's 136KB-LDS 256^2 block = 1 block/CU (Occupancy 21%) -> every
//   lockstep barrier wait was a CU-wide bubble; static-schedule ports of the
//   8-phase template twice failed to fill them. New GEMM: 128x256 tile, 4 waves
//   (wave-tile 128x64 keeps 2.67 MFMA/b128), BK=32 dbuf -> 51KB LDS, ~238
//   regs/wave -> TWO independent blocks/CU provide the overlap via TLP
//   (m97 mechanism). One __syncthreads per K-tile, compiler-scheduled LDS reads.

typedef __attribute__((ext_vector_type(8))) __bf16 bf16x8;
typedef __attribute__((ext_vector_type(4))) float f32x4;

#define BM 128
#define BN 128
#define LDK 40  // fallback path LDS k-stride

static __device__ __forceinline__ ushort f2bf(float x) {  // RNE fp32->bf16
  unsigned u = __float_as_uint(x);
  return (ushort)((u + 0x7fffu + ((u >> 16) & 1u)) >> 16);
}

typedef __attribute__((address_space(1))) void gbl_t;
typedef __attribute__((address_space(3))) void lds_t;
static __device__ __forceinline__ void gl_lds16(const void* g, void* l) {
  __builtin_amdgcn_global_load_lds((gbl_t*)g, (lds_t*)l, 16, 0, 0);
}

static __device__ __forceinline__ bf16x8 cvt8(float4 lo, float4 hi) {
  __hip_bfloat162 c0 = __float22bfloat162_rn({lo.x, lo.y});
  __hip_bfloat162 c1 = __float22bfloat162_rn({lo.z, lo.w});
  __hip_bfloat162 c2 = __float22bfloat162_rn({hi.x, hi.y});
  __hip_bfloat162 c3 = __float22bfloat162_rn({hi.z, hi.w});
  union { int4 i; bf16x8 v; } u;
  u.i.x = *(int*)&c0; u.i.y = *(int*)&c1; u.i.z = *(int*)&c2; u.i.w = *(int*)&c3;
  return u.v;
}

// fast tanh: 1 - 2/(e^{2x}+1). exp(+inf)->inf gives 1; exp(-inf)->0 gives -1.
static __device__ __forceinline__ float tanh_fast(float x) {
  float e = __expf(2.f * x);
  return 1.f - 2.f / (e + 1.f);
}

// ---------- prep: [0,cvt_blocks) feat cvt | +256 W1 transpose | +1024 h2 ----------
__global__ __launch_bounds__(256) void prep_kernel(
    const float* __restrict__ feat_half, ushort* __restrict__ featb,
    const float* __restrict__ W1, ushort* __restrict__ w1t,
    const float* __restrict__ hidden, const float* __restrict__ W2,
    const float* __restrict__ b2, float* __restrict__ h2p, int cvt_blocks) {
  __shared__ float smem[64 * 65];
  const int bx = blockIdx.x, tid = threadIdx.x;
  if (bx < cvt_blocks) {
    // feat fp32 -> bf16, 8 elems/thread
    const size_t i8 = ((size_t)bx * 256 + tid) * 8;
    float4 a = *(const float4*)(feat_half + i8);
    float4 c = *(const float4*)(feat_half + i8 + 4);
    union { bf16x8 v; int4 i; } u;
    u.v = cvt8(a, c);
    *(int4*)(featb + i8) = u.i;
  } else if (bx < cvt_blocks + 256) {
    // W1 [F][D] fp32 -> W1T [D][F] bf16, 64x64 tiles
    const int t = bx - cvt_blocks;
    const int tc = t & 15, tr = t >> 4;
    float (*tt)[65] = (float(*)[65])smem;
    const int r = tid >> 4, c4 = (tid & 15) * 4;
#pragma unroll
    for (int p = 0; p < 4; ++p) {
      const int rr = p * 16 + r;
      float4 v = *(const float4*)(W1 + (size_t)(tr * 64 + rr) * 1024 + tc * 64 + c4);
      tt[rr][c4] = v.x; tt[rr][c4 + 1] = v.y; tt[rr][c4 + 2] = v.z; tt[rr][c4 + 3] = v.w;
    }
    __syncthreads();
    const int cc = tid >> 3, r8 = (tid & 7) * 8;
#pragma unroll
    for (int p = 0; p < 2; ++p) {
      const int c = p * 32 + cc;
      ushort tmp[8];
#pragma unroll
      for (int j = 0; j < 8; ++j) tmp[j] = f2bf(tt[r8 + j][c]);
      *(int4*)(w1t + (size_t)(tc * 64 + c) * 1024 + tr * 64 + r8) = *(int4*)tmp;
    }
  } else {
    // h2p[z][b][d] = hidden[b][128z:+128] @ W2[...,d] (+b2 at z==0)
    const int t = bx - cvt_blocks - 256;  // 0..1023
    const int dblk = t & 3, b = (t >> 2) & 31, z = t >> 7;
    const int d = dblk * 256 + tid;
    const int k0 = z * 128;
    float* h = smem;
    if (tid < 128) h[tid] = hidden[b * 1024 + k0 + tid];
    __syncthreads();
    float acc = (z == 0) ? b2[d] : 0.f;
#pragma unroll 8
    for (int k = 0; k < 128; ++k)
      acc += h[k] * W2[(size_t)(k0 + k) * 1024 + d];
    h2p[z * 32768 + b * 1024 + d] = acc;
  }
}

// ======== PRIMARY: 128x256-tile bf16 GEMM, BK=32, 256 thr / 4 waves ========
// Designed for 2 blocks/CU (51KB LDS, ~238 regs/wave incl. 128 acc):
//   - dbuf LDS: A[2][128][32], B[2][256][32] bf16 (DMA-linear dest).
//   - 16B-chunk XOR swizzle: LDS slot (r,c) holds global chunk (r, c^((r>>1)&3))
//     -> frag reads are <=2-way bank aliased (free).
//   - one __syncthreads per K-tile; compiler schedules ds_read/MFMA interleave
//     (fine lgkmcnt) within the tile; cross-block TLP fills barrier bubbles.
// Each wave computes rows 0..127 x cols wave*64..+64: acc[8][4] f32x4.

#define STAGE_A32(T, BUF) {                                                    \
    gl_lds16(featb + a_go + (T) * 32,         (char*)ldsA + (BUF) * 8192 + lA);\
    gl_lds16(featb + a_go + 65536 + (T) * 32, (char*)ldsA + (BUF) * 8192 + lA + 4096); }
#define STAGE_B32(T, BUF) {                                                    \
    gl_lds16(w1t + b_go + (T) * 32,          (char*)ldsB + (BUF) * 16384 + lA);\
    gl_lds16(w1t + b_go + 65536 + (T) * 32,  (char*)ldsB + (BUF) * 16384 + lA + 4096); \
    gl_lds16(w1t + b_go + 131072 + (T) * 32, (char*)ldsB + (BUF) * 16384 + lA + 8192); \
    gl_lds16(w1t + b_go + 196608 + (T) * 32, (char*)ldsB + (BUF) * 16384 + lA + 12288); }

#define MFMA_B16(AF, IB)                                                       \
  acc[IB][0] = __builtin_amdgcn_mfma_f32_16x16x32_bf16(AF, bfr0, acc[IB][0], 0, 0, 0); \
  acc[IB][1] = __builtin_amdgcn_mfma_f32_16x16x32_bf16(AF, bfr1, acc[IB][1], 0, 0, 0); \
  acc[IB][2] = __builtin_amdgcn_mfma_f32_16x16x32_bf16(AF, bfr2, acc[IB][2], 0, 0, 0); \
  acc[IB][3] = __builtin_amdgcn_mfma_f32_16x16x32_bf16(AF, bfr3, acc[IB][3], 0, 0, 0);

#define TILE32(T, CUR, NXT) {                                                  \
    if ((T) + 1 < 32) { STAGE_A32((T) + 1, NXT); STAGE_B32((T) + 1, NXT); }    \
    bf16x8 bfr0, bfr1, bfr2, bfr3;                                             \
    bfr0 = *(const bf16x8*)&ldsB[CUR][wave * 64 + lrow][cswz8];                \
    bfr1 = *(const bf16x8*)&ldsB[CUR][wave * 64 + 16 + lrow][cswz8];           \
    bfr2 = *(const bf16x8*)&ldsB[CUR][wave * 64 + 32 + lrow][cswz8];           \
    bfr3 = *(const bf16x8*)&ldsB[CUR][wave * 64 + 48 + lrow][cswz8];           \
    _Pragma("unroll") for (int i = 0; i < 8; ++i) {                            \
      const bf16x8 af = *(const bf16x8*)&ldsA[CUR][i * 16 + lrow][cswz8];      \
      MFMA_B16(af, i)                                                          \
    }                                                                          \
    __syncthreads();                                                           \
  }

__global__ __launch_bounds__(256, 2) void gemm_score_tlp_kernel(
    const ushort* __restrict__ featb,  // bf16 [32768][1024]
    const ushort* __restrict__ w1t,    // bf16 [1024][1024]
    const float* __restrict__ b1, const float* __restrict__ h2p,
    const float* __restrict__ wp, float* __restrict__ score_p) {
  __shared__ ushort ldsA[2][128][32];  // 16 KB
  __shared__ ushort ldsB[2][256][32];  // 32 KB
  __shared__ float hbl[256], wpl[256];
  __shared__ float sred[3][128];

  const int tid = threadIdx.x;
  const int row0 = blockIdx.x * 128;
  const int col0 = blockIdx.y * 256;
  const int b = blockIdx.x >> 3;
  const int wave = tid >> 6, lane = tid & 63;
  const int lrow = lane & 15, quad = lane >> 4;
  const int cswz8 = (quad ^ ((lrow >> 1) & 3)) * 8;

  // preloop: hb (b1 + sum of h2 partials) and wp slices for this col block
  {
    const int d = col0 + tid;
    float hv = b1[d];
#pragma unroll
    for (int p = 0; p < 8; ++p) hv += h2p[p * 32768 + b * 1024 + d];
    hbl[tid] = hv;
    wpl[tid] = wp[d];
  }

  // staging offsets: slot s=(wave*64+lane)+256*p covers (row r=s>>2, chunk c=s&3);
  // source chunk q = c ^ ((r>>1)&3). +256 slots = +64 rows, q unchanged ->
  // global offset just +64*1024. LDS dest linear: (wave*64)*16 (+p*4096) +lane*16.
  int a_go, b_go, lA;
  {
    const int s = wave * 64 + lane;
    const int r = s >> 2, c = s & 3;
    const int q = c ^ ((r >> 1) & 3);
    a_go = (row0 + r) * 1024 + q * 8;
    b_go = (col0 + r) * 1024 + q * 8;
    lA = (wave * 64) * 16;  // lane*16 added by LDS-DMA hardware
  }

  f32x4 acc[8][4] = {};

  STAGE_A32(0, 0); STAGE_B32(0, 0);
  __syncthreads();

  for (int t = 0; t < 32; t += 2) {
    TILE32(t, 0, 1);
    TILE32(t + 1, 1, 0);
  }

  // ---- epilogue: score partial per row over this 256-col block ----
  float hbv[4], wpv[4];
#pragma unroll
  for (int j = 0; j < 4; ++j) {
    const int idx = wave * 64 + j * 16 + lrow;
    hbv[j] = hbl[idx];
    wpv[j] = wpl[idx];
  }
  float rs[8][4];
#pragma unroll
  for (int i = 0; i < 8; ++i) {
#pragma unroll
    for (int r = 0; r < 4; ++r) {
      float s = 0.f;
#pragma unroll
      for (int j = 0; j < 4; ++j)
        s += tanh_fast(acc[i][j][r] + hbv[j]) * wpv[j];
      s += __shfl_xor(s, 8);
      s += __shfl_xor(s, 4);
      s += __shfl_xor(s, 2);
      s += __shfl_xor(s, 1);
      rs[i][r] = s;
    }
  }
  if (wave != 0 && lrow == 0) {
#pragma unroll
    for (int i = 0; i < 8; ++i)
#pragma unroll
      for (int r = 0; r < 4; ++r)
        sred[wave - 1][i * 16 + quad * 4 + r] = rs[i][r];
  }
  __syncthreads();
  if (wave == 0 && lrow == 0) {
#pragma unroll
    for (int i = 0; i < 8; ++i)
#pragma unroll
      for (int r = 0; r < 4; ++r) {
        const int ro = i * 16 + quad * 4 + r;
        score_p[(size_t)blockIdx.y * 32768 + row0 + ro] =
            rs[i][r] + sred[0][ro] + sred[1][ro] + sred[2][ro];
      }
  }
}

// ======== FALLBACK (small ws): staging-cvt GEMM, fp32 feat direct ========
#define GEMM_PRELOOP()                                                         \
  if (tid < 128) {                                                             \
    const int d = col0 + tid;                                                  \
    float hv = b1[d];                                                          \
    _Pragma("unroll") for (int p = 0; p < 8; ++p)                              \
        hv += h2p[p * 32768 + b * 1024 + d];                                   \
    hbl[tid] = hv;                                                             \
  } else {                                                                     \
    wpl[tid - 128] = wp[col0 + tid - 128];                                     \
  }

#define GEMM_EPILOGUE(ROWG)                                                    \
  float hbv[4], wpv[4];                                                        \
  _Pragma("unroll") for (int j = 0; j < 4; ++j) {                              \
    const int idx = wn * 64 + j * 16 + lrow;                                   \
    hbv[j] = hbl[idx];                                                         \
    wpv[j] = wpl[idx];                                                         \
  }                                                                            \
  float rsum[4][4];                                                            \
  _Pragma("unroll") for (int i = 0; i < 4; ++i) {                              \
    _Pragma("unroll") for (int r = 0; r < 4; ++r) {                            \
      float s = 0.f;                                                           \
      _Pragma("unroll") for (int j = 0; j < 4; ++j)                            \
          s += tanh_fast(acc[i][j][r] + hbv[j]) * wpv[j];                      \
      s += __shfl_xor(s, 8);                                                   \
      s += __shfl_xor(s, 4);                                                   \
      s += __shfl_xor(s, 2);                                                   \
      s += __shfl_xor(s, 1);                                                   \
      rsum[i][r] = s;                                                          \
    }                                                                          \
  }                                                                            \
  if (wn == 1 && lrow == 0) {                                                  \
    _Pragma("unroll") for (int i = 0; i < 4; ++i)                              \
        _Pragma("unroll") for (int r = 0; r < 4; ++r)                          \
            sred[wm][i * 16 + quad * 4 + r] = rsum[i][r];                      \
  }                                                                            \
  __syncthreads();                                                             \
  if (wn == 0 && lrow == 0) {                                                  \
    _Pragma("unroll") for (int i = 0; i < 4; ++i)                              \
        _Pragma("unroll") for (int r = 0; r < 4; ++r) {                        \
          const int ro = wm * 64 + i * 16 + quad * 4 + r;                      \
          score_p[(size_t)blockIdx.y * 32768 + (ROWG) + ro] =                  \
              rsum[i][r] + sred[wm][ro & 63];                                  \
        }                                                                      \
  }

__global__ __launch_bounds__(256) void gemm_score_cvt_kernel(
    const float* __restrict__ feat, const ushort* __restrict__ w1t,
    const float* __restrict__ b1, const float* __restrict__ h2p,
    const float* __restrict__ wp, float* __restrict__ score_p) {
  __shared__ ushort ldsA[BM * LDK];
  __shared__ ushort ldsB[BN * LDK];
  __shared__ float sred[2][64];
  __shared__ float hbl[128], wpl[128];
  const int tid = threadIdx.x;
  const int row0 = blockIdx.x * BM;
  const int col0 = blockIdx.y * BN;
  const int b = row0 >> 10;

  const int wave = tid >> 6, lane = tid & 63;
  const int wm = wave & 1, wn = wave >> 1;
  const int lrow = lane & 15, quad = lane >> 4;

  GEMM_PRELOOP()

  const int arow = tid >> 1;
  const int akof = (tid & 1) * 16;
  const int brow = tid >> 2;
  const int bkof = (tid & 3) * 8;

  f32x4 acc[4][4] = {};

  for (int k0 = 0; k0 < 1024; k0 += 32) {
    {
      const float* ap = feat + (size_t)(row0 + arow) * 1024 + k0 + akof;
      float4 v0 = *(const float4*)(ap + 0);
      float4 v1 = *(const float4*)(ap + 4);
      float4 v2 = *(const float4*)(ap + 8);
      float4 v3 = *(const float4*)(ap + 12);
      union { bf16x8 v; int4 i; } w0, w1;
      w0.v = cvt8(v0, v1);
      w1.v = cvt8(v2, v3);
      *(int4*)&ldsA[arow * LDK + akof] = w0.i;
      *(int4*)&ldsA[arow * LDK + akof + 8] = w1.i;
    }
#pragma unroll
    for (int p = 0; p < 2; ++p) {
      const int m = p * 64 + brow;
      *(int4*)&ldsB[m * LDK + bkof] =
          *(const int4*)(w1t + (size_t)(col0 + m) * 1024 + k0 + bkof);
    }
    __syncthreads();
    bf16x8 af[4], bfr[4];
#pragma unroll
    for (int i = 0; i < 4; ++i)
      af[i] = *(const bf16x8*)&ldsA[(wm * 64 + i * 16 + lrow) * LDK + quad * 8];
#pragma unroll
    for (int j = 0; j < 4; ++j)
      bfr[j] = *(const bf16x8*)&ldsB[(wn * 64 + j * 16 + lrow) * LDK + quad * 8];
#pragma unroll
    for (int i = 0; i < 4; ++i)
#pragma unroll
      for (int j = 0; j < 4; ++j)
        acc[i][j] = __builtin_amdgcn_mfma_f32_16x16x32_bf16(
            af[i], bfr[j], acc[i][j], 0, 0, 0);
    __syncthreads();
  }

  GEMM_EPILOGUE(row0)
}

// -------- softmax over L per b (sums np partials); also zeroes out[b][:] --------
__global__ __launch_bounds__(256) void softmax_kernel(
    const float* __restrict__ score_p, float* __restrict__ w,
    float* __restrict__ out, int np) {
  const int b = blockIdx.x, tid = threadIdx.x;
  const int lane = tid & 63, wv = tid >> 6;
  __shared__ float sm[4], ss[4];
  float v[4];
  float mx = -1e30f;
#pragma unroll
  for (int i = 0; i < 4; ++i) {
    const int idx = b * 1024 + i * 256 + tid;
    out[idx] = 0.f;  // d_out poisoned; context atomicAdds later
    float s = 0.f;
    for (int p = 0; p < np; ++p) s += score_p[p * 32768 + idx];
    v[i] = s;
    mx = fmaxf(mx, s);
  }
#pragma unroll
  for (int off = 32; off; off >>= 1) mx = fmaxf(mx, __shfl_xor(mx, off));
  if (lane == 0) sm[wv] = mx;
  __syncthreads();
  mx = fmaxf(fmaxf(sm[0], sm[1]), fmaxf(sm[2], sm[3]));
  float sum = 0.f;
#pragma unroll
  for (int i = 0; i < 4; ++i) {
    v[i] = __expf(v[i] - mx);
    sum += v[i];
  }
#pragma unroll
  for (int off = 32; off; off >>= 1) sum += __shfl_xor(sum, off);
  if (lane == 0) ss[wv] = sum;
  __syncthreads();
  const float inv = 1.f / (ss[0] + ss[1] + ss[2] + ss[3]);
#pragma unroll
  for (int i = 0; i < 4; ++i) w[b * 1024 + i * 256 + tid] = v[i] * inv;
}

// -------- out[b][f] += sum_{l in 64-chunk} w[b][l]*feat[b][l][f] (fp32) --------
__global__ __launch_bounds__(256) void context_kernel(
    const float* __restrict__ w, const float* __restrict__ feat,
    float* __restrict__ out) {
  const int b = blockIdx.y;
  const int l0 = blockIdx.x * 64;
  const int f0 = threadIdx.x * 4;
  __shared__ float wl[64];
  if (threadIdx.x < 64) wl[threadIdx.x] = w[b * 1024 + l0 + threadIdx.x];
  __syncthreads();
  const float* fb = feat + (size_t)b * 1048576 + (size_t)l0 * 1024 + f0;
  float a0 = 0.f, a1 = 0.f, a2 = 0.f, a3 = 0.f;
#pragma unroll 8
  for (int l = 0; l < 64; ++l) {
    float4 v = *(const float4*)(fb + (size_t)l * 1024);
    const float wv = wl[l];
    a0 += wv * v.x;
    a1 += wv * v.y;
    a2 += wv * v.z;
    a3 += wv * v.w;
  }
  float* dst = out + b * 1024 + f0;
  atomicAdd(dst + 0, a0);
  atomicAdd(dst + 1, a1);
  atomicAdd(dst + 2, a2);
  atomicAdd(dst + 3, a3);
}

extern "C" void kernel_launch(void* const* d_in, const int* in_sizes, int n_in,
                              void* d_out, int out_size, void* d_ws, size_t ws_size,
                              hipStream_t stream) {
  const float* feat   = (const float*)d_in[0];
  const float* hidden = (const float*)d_in[1];
  const float* W1     = (const float*)d_in[2];
  const float* b1     = (const float*)d_in[3];
  const float* W2     = (const float*)d_in[4];
  const float* b2     = (const float*)d_in[5];
  const float* Wp     = (const float*)d_in[6];
  float* out = (float*)d_out;

  char* ws = (char*)d_ws;
  ushort* w1t    = (ushort*)ws;                  // 2 MB
  float* score_p = (float*)(ws + 2097152);       // 1 MB region ([4] or [8] x 32768)
  float* h2p     = (float*)(ws + 3145728);       // 1 MB [8][32768]
  float* wts     = (float*)(ws + 4194304);       // 128 KB
  ushort* featb  = (ushort*)(ws + 4325376);      // 64 MB (primary path only)
  const bool big_ws = ws_size >= (size_t)(4325376 + 67108864);

  if (big_ws) {
    // full-batch prep: cvt 16384 blocks + transpose 256 + h2 1024
    prep_kernel<<<17664, 256, 0, stream>>>(feat, featb, W1, w1t, hidden, W2, b2,
                                           h2p, 16384);
    gemm_score_tlp_kernel<<<dim3(256, 4), 256, 0, stream>>>(featb, w1t, b1, h2p,
                                                            Wp, score_p);
    softmax_kernel<<<32, 256, 0, stream>>>(score_p, wts, out, 4);
  } else {
    prep_kernel<<<1280, 256, 0, stream>>>(feat, featb, W1, w1t, hidden, W2, b2,
                                          h2p, 0);
    gemm_score_cvt_kernel<<<dim3(256, 8), 256, 0, stream>>>(feat, w1t, b1, h2p,
                                                            Wp, score_p);
    softmax_kernel<<<32, 256, 0, stream>>>(score_p, wts, out, 8);
  }

  context_kernel<<<dim3(16, 32), 256, 0, stream>>>(wts, feat, out);
}